// Round 3
// baseline (255.742 us; speedup 1.0000x reference)
//
#include <hip/hip_runtime.h>
#include <hip/hip_bf16.h>

#define N_NODES 100000
#define N_EDGES 1600000
#define D 128
#define N_TILES 6250             // N_NODES/16
#define NB 512                   // buckets
#define RPB 196                  // rows per bucket (512*196 = 100352 >= N_NODES)
#define BCAP 3584                // slab capacity: mean 3136 + 8 sigma (R9-validated margin)
#define SA_EDGES 3125            // edges per scatterA WG (512*3125 = 1.6M exact)
#define CAP 16                   // LDS staging depth per bucket (R0-proven config)
#define NCH 13                   // col chunks of 8192 rows (2MB bf16 slice, fits XCD L2)
#define BPC 208                  // bins per chunk = 16 waves * 13 slots
#define KEYS 2704                // NCH*BPC
#define KEYP 2752                // padded to 64*43 for single-wave scan

typedef __bf16 bf16x8 __attribute__((ext_vector_type(8)));
typedef float  f32x4  __attribute__((ext_vector_type(4)));
typedef float  f32x2  __attribute__((ext_vector_type(2)));
typedef int    i32x2  __attribute__((ext_vector_type(2)));

// ---- K1: W transpose (fp32 -> bf16 WT) + zero bucket cursors ----
__global__ __launch_bounds__(256) void prep_kernel(const float* __restrict__ W,
                                                   __bf16* __restrict__ WT,
                                                   int* __restrict__ bucketCnt) {
    int t = blockIdx.x * 256 + threadIdx.x;   // 16384 threads
    int k = t >> 7, n = t & 127;
    WT[n * D + k] = (__bf16)W[t];
    if (t < NB) bucketCnt[t] = 0;
}

// ---- K2: GEMM h = bf16(x) @ bf16(W) (verified since R6) ----
__global__ __launch_bounds__(256) void gemm_kernel(
        const float* __restrict__ x,
        const __bf16* __restrict__ WT,
        __bf16* __restrict__ h) {
    __shared__ __bf16 lsm[4][16][144];
    const int wave = threadIdx.x >> 6;
    const int lane = threadIdx.x & 63;
    const int tile = blockIdx.x * 4 + wave;
    if (tile >= N_TILES) return;
    const int m = lane & 15, quad = lane >> 4;
    const float* xp = x + (size_t)(tile * 16 + m) * D + quad * 8;

    f32x4 acc[8];
#pragma unroll
    for (int ct = 0; ct < 8; ++ct) acc[ct] = (f32x4)(0.0f);
#pragma unroll
    for (int kk = 0; kk < 4; ++kk) {
        f32x4 a0 = *(const f32x4*)(xp + kk * 32);
        f32x4 a1 = *(const f32x4*)(xp + kk * 32 + 4);
        bf16x8 a;
#pragma unroll
        for (int j = 0; j < 4; ++j) { a[j] = (__bf16)a0[j]; a[j + 4] = (__bf16)a1[j]; }
#pragma unroll
        for (int ct = 0; ct < 8; ++ct) {
            bf16x8 b = *(const bf16x8*)(WT + (size_t)(ct * 16 + m) * D + kk * 32 + quad * 8);
            acc[ct] = __builtin_amdgcn_mfma_f32_16x16x32_bf16(a, b, acc[ct], 0, 0, 0);
        }
    }
#pragma unroll
    for (int ct = 0; ct < 8; ++ct)
#pragma unroll
        for (int r = 0; r < 4; ++r)
            lsm[wave][quad * 4 + r][ct * 16 + m] = (__bf16)acc[ct][r];
#pragma unroll
    for (int i = 0; i < 4; ++i) {
        int rl = i * 4 + quad;
        bf16x8 vv = *(const bf16x8*)&lsm[wave][rl][m * 8];
        *(bf16x8*)(h + (size_t)(tile * 16 + rl) * D + m * 8) = vv;
    }
}

// ---- K3: LDS-staged scatter into fixed-capacity bucket slabs (R0-proven) ----
// pack = (localRow<<17) | col, val as bits; claims via global per-bucket cursor
__global__ __launch_bounds__(256) void scatterA_kernel(
        const int* __restrict__ rows, const int* __restrict__ cols,
        const float* __restrict__ vals,
        int* __restrict__ bucketCnt, i32x2* __restrict__ svcA) {
    __shared__ i32x2 buf[NB][CAP];   // 64 KB
    __shared__ int   cnt[NB];        // 2 KB
    for (int t = threadIdx.x; t < NB; t += 256) cnt[t] = 0;
    __syncthreads();
    const int base = blockIdx.x * SA_EDGES;
    for (int it = 0; it < 13; ++it) {
        int idx = it * 256 + threadIdx.x;
        if (idx < SA_EDGES) {
            int e = base + idx;
            int r = rows[e];
            int b = r / RPB;                  // magic-mul division by 196
            int local = r - b * RPB;
            i32x2 pk;
            pk[0] = (local << 17) | cols[e];
            pk[1] = __float_as_int(vals[e]);
            int p = atomicAdd(&cnt[b], 1);
            if (p < CAP) buf[b][p] = pk;
            else {                             // rare overflow: direct claim
                int g = atomicAdd(&bucketCnt[b], 1);
                if (g < BCAP) svcA[(size_t)b * BCAP + g] = pk;
            }
        }
    }
    __syncthreads();
    for (int t = threadIdx.x; t < NB; t += 256) {
        int n = min(cnt[t], CAP);
        if (n > 0) {
            int g = atomicAdd(&bucketCnt[t], n);
            i32x2* dst = svcA + (size_t)t * BCAP;
            for (int i = 0; i < n; ++i)
                if (g + i < BCAP) dst[g + i] = buf[t][i];   // contiguous run
        }
    }
}

// ---- K4: chunked sort with wave-contiguous permuted key + segsum + relu ----
// key = chunk*208 + (row&15)*13 + (row>>4): within a chunk, each wave's 13
// rows are ADJACENT bins -> its edges are one contiguous lbuf range, bin
// start = previous bin end (cursor i carries across rows), lbuf/send reads
// are wave-broadcast. Accumulators are 13 NAMED f32x2 registers (rule #20:
// no arrays, no dynamic indexing -> no scratch).
__device__ __forceinline__ f32x2 bf2f(unsigned u) {
    f32x2 r;
    r[0] = __int_as_float(u << 16);
    r[1] = __int_as_float(u & 0xffff0000u);
    return r;
}

__device__ __forceinline__ int sortkey(unsigned u) {
    // u = (localRow<<17) | col ; chunk = col>>13 (0..12)
    int rl = (int)(u >> 17);
    int c  = (int)((u >> 13) & 15u);
    return c * BPC + (rl & 15) * 13 + (rl >> 4);
}

__global__ __launch_bounds__(1024, 8) void sortsum_kernel(
        const __bf16* __restrict__ h, const int* __restrict__ bucketCnt,
        const i32x2* __restrict__ svcA, float* __restrict__ out) {
    __shared__ i32x2 lbuf[BCAP];     // 28672 B
    __shared__ int   lhist[KEYP];    // 11008 B
    __shared__ int   send[KEYP];     // inclusive scan (bin ends)
    __shared__ int   lcur[KEYP];     // scatter cursors (bin starts, mutated)
    const int b   = blockIdx.x;
    const int tid = threadIdx.x;
    const int n   = min(bucketCnt[b], BCAP);
    const i32x2* win = svcA + (size_t)b * BCAP;

    for (int t = tid; t < KEYP; t += 1024) lhist[t] = 0;
    __syncthreads();

    // load window into registers (<=4 recs/thread) + LDS histogram over keys
    i32x2 rec0, rec1, rec2, rec3;
    const int i0 = tid, i1 = tid + 1024, i2 = tid + 2048, i3 = tid + 3072;
    if (i0 < n) { rec0 = win[i0]; atomicAdd(&lhist[sortkey((unsigned)rec0[0])], 1); }
    if (i1 < n) { rec1 = win[i1]; atomicAdd(&lhist[sortkey((unsigned)rec1[0])], 1); }
    if (i2 < n) { rec2 = win[i2]; atomicAdd(&lhist[sortkey((unsigned)rec2[0])], 1); }
    if (i3 < n) { rec3 = win[i3]; atomicAdd(&lhist[sortkey((unsigned)rec3[0])], 1); }
    __syncthreads();

    // single-wave scan over 2752 bins: 43 contiguous bins per lane + shuffle scan
    if (tid < 64) {
        const int base = tid * 43;
        int run = 0;
        for (int j = 0; j < 43; ++j) run += lhist[base + j];
        int s = run;
#pragma unroll
        for (int d = 1; d < 64; d <<= 1) {
            int t2 = __shfl_up(s, d, 64);
            if (tid >= d) s += t2;
        }
        int acc = s - run;               // exclusive prefix of this 43-bin group
        for (int j = 0; j < 43; ++j) {
            int hv = lhist[base + j];
            lcur[base + j] = acc;
            acc += hv;
            send[base + j] = acc;
        }
    }
    __syncthreads();

    // scatter registers into (chunk, wave, slot)-sorted LDS
    if (i0 < n) { lbuf[atomicAdd(&lcur[sortkey((unsigned)rec0[0])], 1)] = rec0; }
    if (i1 < n) { lbuf[atomicAdd(&lcur[sortkey((unsigned)rec1[0])], 1)] = rec1; }
    if (i2 < n) { lbuf[atomicAdd(&lcur[sortkey((unsigned)rec2[0])], 1)] = rec2; }
    if (i3 < n) { lbuf[atomicAdd(&lcur[sortkey((unsigned)rec3[0])], 1)] = rec3; }
    __syncthreads();

    // chunk-swept segsum: per chunk, the wave's 13 row-slots are contiguous
    // bins; cursor i runs through the wave's contiguous edge range.
    const int wave = tid >> 6;
    const int lane = tid & 63;
    const char* hb = (const char*)h;
    const unsigned lo4 = (unsigned)lane * 4u;

    f32x2 A0 = (f32x2)(0.0f), A1 = (f32x2)(0.0f), A2  = (f32x2)(0.0f);
    f32x2 A3 = (f32x2)(0.0f), A4 = (f32x2)(0.0f), A5  = (f32x2)(0.0f);
    f32x2 A6 = (f32x2)(0.0f), A7 = (f32x2)(0.0f), A8  = (f32x2)(0.0f);
    f32x2 A9 = (f32x2)(0.0f), A10 = (f32x2)(0.0f), A11 = (f32x2)(0.0f);
    f32x2 A12 = (f32x2)(0.0f);

#define ROW(J, AJ)                                                              \
    {                                                                           \
        const int e_ = send[kb + (J)];                                          \
        for (; i + 1 < e_; i += 2) {                                            \
            i32x2 q0 = lbuf[i], q1 = lbuf[i + 1];                               \
            unsigned u0 = *(const unsigned*)(hb + ((((unsigned)q0[0]) & 0x1FFFFu) << 8) + lo4); \
            unsigned u1 = *(const unsigned*)(hb + ((((unsigned)q1[0]) & 0x1FFFFu) << 8) + lo4); \
            AJ += bf2f(u0) * __int_as_float(q0[1]);                             \
            AJ += bf2f(u1) * __int_as_float(q1[1]);                             \
        }                                                                       \
        if (i < e_) {                                                           \
            i32x2 q0 = lbuf[i]; ++i;                                            \
            unsigned u0 = *(const unsigned*)(hb + ((((unsigned)q0[0]) & 0x1FFFFu) << 8) + lo4); \
            AJ += bf2f(u0) * __int_as_float(q0[1]);                             \
        }                                                                       \
    }

    for (int c = 0; c < NCH; ++c) {
        const int kb = c * BPC + wave * 13;
        int i = kb ? send[kb - 1] : 0;
        ROW(0, A0)  ROW(1, A1)  ROW(2, A2)  ROW(3, A3)
        ROW(4, A4)  ROW(5, A5)  ROW(6, A6)  ROW(7, A7)
        ROW(8, A8)  ROW(9, A9)  ROW(10, A10) ROW(11, A11)
        ROW(12, A12)
    }
#undef ROW

    // epilogue: relu + store (slot J -> local row J*16 + wave)
#define STORE(J, AJ)                                                            \
    {                                                                           \
        const int rl = (J) * 16 + wave;                                         \
        const int gr = b * RPB + rl;                                            \
        if (rl < RPB && gr < N_NODES) {                                         \
            f32x2 o;                                                            \
            o[0] = fmaxf(AJ[0], 0.0f);                                          \
            o[1] = fmaxf(AJ[1], 0.0f);                                          \
            __builtin_nontemporal_store(o, (f32x2*)(out + (size_t)gr * D + lane * 2)); \
        }                                                                       \
    }
    STORE(0, A0)  STORE(1, A1)  STORE(2, A2)  STORE(3, A3)
    STORE(4, A4)  STORE(5, A5)  STORE(6, A6)  STORE(7, A7)
    STORE(8, A8)  STORE(9, A9)  STORE(10, A10) STORE(11, A11)
    STORE(12, A12)
#undef STORE
}

extern "C" void kernel_launch(void* const* d_in, const int* in_sizes, int n_in,
                              void* d_out, int out_size, void* d_ws, size_t ws_size,
                              hipStream_t stream) {
    const float* x    = (const float*)d_in[0];
    const float* w    = (const float*)d_in[1];
    const float* vals = (const float*)d_in[2];
    const int*   rows = (const int*)d_in[3];
    const int*   cols = (const int*)d_in[4];
    float*       out  = (float*)d_out;

    // ---- workspace (~40.3 MB) ----
    char* p = (char*)d_ws;
    __bf16* h         = (__bf16*)p;  p += (size_t)N_NODES * D * 2;          // 25.6 MB
    __bf16* WT        = (__bf16*)p;  p += (size_t)D * D * 2;                // 32 KB
    int*    bucketCnt = (int*)p;     p += 4096;                             // NB ints
    i32x2*  svcA      = (i32x2*)p;   p += (size_t)NB * BCAP * 8;            // 14.7 MB

    prep_kernel<<<64, 256, 0, stream>>>(w, WT, bucketCnt);
    gemm_kernel<<<(N_TILES + 3) / 4, 256, 0, stream>>>(x, WT, h);
    scatterA_kernel<<<NB, 256, 0, stream>>>(rows, cols, vals, bucketCnt, svcA);
    sortsum_kernel<<<NB, 1024, 0, stream>>>(h, bucketCnt, svcA, out);
}